// Round 6
// baseline (857.590 us; speedup 1.0000x reference)
//
#include <hip/hip_runtime.h>
#include <hip/hip_bf16.h>

#define TT 512
#define MCELLS 16384            // B*N = 256*64
#define LOG2E 1.44269504088896340736f
#define LN2   0.69314718055994530942f

typedef __attribute__((ext_vector_type(8))) short bf16x8;
typedef __attribute__((ext_vector_type(4))) float f32x4;

__device__ __forceinline__ short f2bf(float f) {
    __hip_bfloat16 h = __float2bfloat16(f);
    return __builtin_bit_cast(short, h);
}
// two f32 -> packed bf16 dword (low16 = a, high16 = b), RNE in HW
__device__ __forceinline__ unsigned cvtpk(float a, float b) {
    unsigned r;
    asm("v_cvt_pk_bf16_f32 %0, %1, %2" : "=v"(r) : "v"(a), "v"(b));
    return r;
}

// Eigen-float rational tanh core: tanh(x) ~= N/D, N = xc*P(xc^2), D = Q(xc^2),
// xc clamped to +-7.9053. ~1e-6 accurate on the clamp range; division is left
// to the caller so it can be folded into a shared rcp.
__device__ __forceinline__ void tanh_nd(float x, float& N, float& D) {
    const float xc = __builtin_amdgcn_fmed3f(x, -7.90531110763549805f,
                                                 7.90531110763549805f);
    const float u  = xc * xc;
    float p = -2.76076847742355e-16f;
    p = fmaf(p, u, 2.00018790482477e-13f);
    p = fmaf(p, u, -8.60467152213735e-11f);
    p = fmaf(p, u, 5.12229709037114e-08f);
    p = fmaf(p, u, 1.48572235717979e-05f);
    p = fmaf(p, u, 6.37261928875436e-04f);
    p = fmaf(p, u, 4.89352455891786e-03f);
    N = xc * p;
    float q = 1.19825839466702e-06f;
    q = fmaf(q, u, 1.18534705686654e-04f);
    q = fmaf(q, u, 2.26843463243900e-03f);
    q = fmaf(q, u, 4.89352518554385e-03f);
    D = q;
}

// Persistent LSTM. grid = 1024 blocks x 256 threads (4 waves) = 4 blocks/CU
// evenly over 256 CUs. Each block owns 16 cells (cell = blockIdx*16+(lane&15));
// wave w handles hdims [w*16, w*16+16) for all 4 gates (jm tile = gate*4+w).
// Swapped MFMA D[gate-rows, cell], A = W_hh VGPR-resident, B = h^T from LDS.
// K=96: 3rd MFMA carries x*W_ih + bias. Activations: sigmoids via exp2 (trans
// pipe), tanh via Eigen rational (VALU pipe) -- balances the two pipes
// (trans/elem 7 -> 5: 3 exp2 + 2 shared rcp).
__global__ __launch_bounds__(256, 4)
void lstm_net_kernel(const float* __restrict__ input,
                     const float* __restrict__ w1,
                     const float* __restrict__ b1,
                     const float* __restrict__ w2,
                     const float* __restrict__ b2,
                     const float* __restrict__ W_ih,
                     const float* __restrict__ W_hh,
                     const float* __restrict__ b_ih,
                     const float* __restrict__ b_hh,
                     const float* __restrict__ wg,
                     const float* __restrict__ bg,
                     float* __restrict__ out)
{
    // h double buffer: 2 x 16 rows(cells) x 144B
    __shared__ __align__(16) char hbuf[2 * 16 * 144];
    __shared__ float gpart[4][4][16];   // ring: slot t&3 written @t, read @t+2

    const int tid  = threadIdx.x;
    const int wv   = tid >> 6;          // 0..3: 16-hdim slice
    const int lane = tid & 63;
    const int lo   = lane & 15;
    const int hi   = lane >> 4;

    for (int o = tid; o < (2 * 16 * 144) / 4; o += 256)
        ((unsigned*)hbuf)[o] = 0u;      // h0 = 0 (both buffers)

    // ---- per-cell constants ----
    const int cell = blockIdx.x * 16 + lo;
    const int n    = cell & 63;
    float a_n = 0.f, c_n = 0.f;
    #pragma unroll
    for (int k = 0; k < 10; ++k) {
        a_n += w1[n * 10 + k] * w2[n * 10 + k];   // per-neuron affine collapse
        c_n += b1[n * 10 + k] * w2[n * 10 + k];
    }
    c_n += b2[n];
    const f32x4 wgv = *(const f32x4*)(wg + wv * 16 + hi * 4);
    const float bgv = bg[0];

    // ---- A-fragments resident in VGPRs ----
    bf16x8 AWf[4][3];
    #pragma unroll
    for (int g = 0; g < 4; ++g) {
        const int row = (g * 4 + wv) * 16 + lo;
        #pragma unroll
        for (int kk = 0; kk < 2; ++kk) {
            const float* src = W_hh + row * 64 + kk * 32 + hi * 8;
            bf16x8 v;
            #pragma unroll
            for (int e = 0; e < 8; ++e) v[e] = f2bf(src[e]);
            AWf[g][kk] = v;
        }
        bf16x8 vx = {};                 // K-ext: col64 = W_ih, col65 = bias
        if (hi == 0) {
            vx[0] = f2bf(W_ih[row]);
            vx[1] = f2bf(b_ih[row] + b_hh[row]);
        }
        AWf[g][2] = vx;
    }

    const f32x4 zero4 = {0.f, 0.f, 0.f, 0.f};
    f32x4 cst = zero4;
    float sp0 = 0.f;
    const float* inP  = input + cell;
    float*       outP = out + cell;
    float raw_next = inP[0];

    __syncthreads();

    for (int t = 0; t < TT; ++t) {
        const float raw = raw_next;
        raw_next = inP[((t + 1 < TT) ? (t + 1) : t) * MCELLS];
        const float x = raw * a_n + c_n;            // outLin[t,cell]

        // B-ext frag: rows 64..95 of B = [x, 1, 0...] (per cell = lo)
        bf16x8 bx = {};
        {
            const short xb = f2bf(x);
            bx[0] = (hi == 0) ? xb : (short)0;
            bx[1] = (hi == 0) ? (short)0x3F80 : (short)0;   // bf16(1.0)
        }

        // h B-frags: cell = lo, hdims hi*8.. / 32+hi*8..
        const char* hrd = hbuf + (t & 1) * 2304 + lo * 144;
        const bf16x8 bf0 = *(const bf16x8*)(hrd + hi * 16);
        const bf16x8 bf1 = *(const bf16x8*)(hrd + 64 + hi * 16);

        f32x4 acc[4];
        #pragma unroll
        for (int g = 0; g < 4; ++g) {
            acc[g] = __builtin_amdgcn_mfma_f32_16x16x32_bf16(AWf[g][2], bx,  zero4, 0, 0, 0);
            acc[g] = __builtin_amdgcn_mfma_f32_16x16x32_bf16(AWf[g][0], bf0, acc[g], 0, 0, 0);
            acc[g] = __builtin_amdgcn_mfma_f32_16x16x32_bf16(AWf[g][1], bf1, acc[g], 0, 0, 0);
        }

        // softplus(x-1), only wave 0 needs it
        float sp = 0.f;
        if (wv == 0) {
            const float spE = __builtin_amdgcn_exp2f(LOG2E * (x - 1.f));
            sp = LN2 * __builtin_amdgcn_logf(1.f + spE);
        }

        // activations: lane handles (cell=lo, hdim = wv*16 + hi*4 + r)
        float gacc = 0.f;
        float hv[4];
        #pragma unroll
        for (int r = 0; r < 4; ++r) {
            const float ip = acc[0][r];
            const float fp = acc[1][r];
            const float gp = acc[2][r];
            const float op = acc[3][r];

            // sigmoid denominators via exp2 (trans pipe)
            const float Id = 1.f + __builtin_amdgcn_exp2f(-LOG2E * ip);
            const float Fd = 1.f + __builtin_amdgcn_exp2f(-LOG2E * fp);
            const float Od = 1.f + __builtin_amdgcn_exp2f(-LOG2E * op);

            // tanh(g) = Ng/Qg via rational (VALU pipe)
            float Ng, Qg;
            tanh_nd(gp, Ng, Qg);

            // c' = c/Fd + Ng/(Qg*Id) = [c*Id*Qg + Ng*Fd] / (Fd*Id*Qg), 1 rcp
            const float cId = cst[r] * Id;
            const float num = fmaf(Ng, Fd, cId * Qg);
            const float den = Fd * (Id * Qg);
            const float cp  = num * __builtin_amdgcn_rcpf(den);
            cst[r] = cp;

            // h = tanh(c')/Od = Nc/(Qc*Od), 1 rcp
            float Nc, Qc;
            tanh_nd(cp, Nc, Qc);
            const float h = Nc * __builtin_amdgcn_rcpf(Qc * Od);

            hv[r] = h;
            gacc += h * wgv[r];
        }
        // h-write: hdims wv*16 + hi*4 .. +4 at row lo
        uint2 pk;
        pk.x = cvtpk(hv[0], hv[1]);
        pk.y = cvtpk(hv[2], hv[3]);
        *(uint2*)(hbuf + ((t + 1) & 1) * 2304 + lo * 144 + wv * 32 + hi * 8) = pk;

        // per-wave partial of g_t = sum_h h*wg (this wave's 16 hdims)
        gacc += __shfl_xor(gacc, 16);
        gacc += __shfl_xor(gacc, 32);
        if (hi == 0) gpart[t & 3][wv][lo] = gacc;

        // output: out[t] = g_prev[t] * sp[t]; g_prev = {g_0, 1, g_{t-2}...}
        if (wv == 0) {
            if (t == 0) {
                sp0 = sp;
            } else if (t == 1) {
                if (hi == 0) outP[MCELLS] = sp;
            } else {
                const int s = (t - 2) & 3;
                const float g = gpart[s][0][lo] + gpart[s][1][lo] +
                                gpart[s][2][lo] + gpart[s][3][lo] + bgv;
                if (hi == 0) {
                    outP[t * MCELLS] = g * sp;
                    if (t == 2) outP[0] = g * sp0;   // g_prev[0] = g_0
                }
            }
        }
        __syncthreads();   // h(t+1) visible; gpart ring ordered
    }
}

extern "C" void kernel_launch(void* const* d_in, const int* in_sizes, int n_in,
                              void* d_out, int out_size, void* d_ws, size_t ws_size,
                              hipStream_t stream) {
    const float* input = (const float*)d_in[0];
    const float* w1    = (const float*)d_in[1];
    const float* b1    = (const float*)d_in[2];
    const float* w2    = (const float*)d_in[3];
    const float* b2    = (const float*)d_in[4];
    const float* W_ih  = (const float*)d_in[5];
    const float* W_hh  = (const float*)d_in[6];
    const float* b_ih  = (const float*)d_in[7];
    const float* b_hh  = (const float*)d_in[8];
    const float* wg    = (const float*)d_in[9];
    const float* bg    = (const float*)d_in[10];

    lstm_net_kernel<<<dim3(1024), dim3(256), 0, stream>>>(
        input, w1, b1, w2, b2, W_ih, W_hh, b_ih, b_hh, wg, bg, (float*)d_out);
}

// Round 7
// 734.579 us; speedup vs baseline: 1.1675x; 1.1675x over previous
//
#include <hip/hip_runtime.h>
#include <hip/hip_bf16.h>

#define TT 512
#define MCELLS 16384            // B*N = 256*64
#define LOG2E 1.44269504088896340736f
#define LN2   0.69314718055994530942f

typedef __attribute__((ext_vector_type(8))) short bf16x8;
typedef __attribute__((ext_vector_type(4))) float f32x4;
typedef __attribute__((ext_vector_type(4))) unsigned u32x4;

__device__ __forceinline__ short f2bf(float f) {
    __hip_bfloat16 h = __float2bfloat16(f);
    return __builtin_bit_cast(short, h);
}
// two f32 -> packed bf16 dword (low16 = a, high16 = b), RNE in HW
__device__ __forceinline__ unsigned cvtpk(float a, float b) {
    unsigned r;
    asm("v_cvt_pk_bf16_f32 %0, %1, %2" : "=v"(r) : "v"(a), "v"(b));
    return r;
}

// Persistent LSTM. grid = 1024 blocks x 256 threads (4 waves) = 4 blocks/CU
// over all 256 CUs. Block owns 16 cells (cell = blockIdx*16 + (lane&15));
// wave w handles hdims [w*16, w*16+16) for all 4 gates (jm tile = gate*4+w).
// Swapped MFMA D[gate-rows, cell], A = W_hh VGPR-resident, B = h^T from LDS.
// K=96: 3rd MFMA carries x*W_ih + bias (B-ext rows = [x, 1]).
// g_t = h.wg computed by 2 more MFMAs (A row0 = wg) -- no shuffle reduction,
// no gpart LDS ring. Output (softplus + store) round-robins across waves
// (t&3 == wv) so no single SIMD hosts all the epilogue work.
__global__ __launch_bounds__(256, 4)
void lstm_net_kernel(const float* __restrict__ input,
                     const float* __restrict__ w1,
                     const float* __restrict__ b1,
                     const float* __restrict__ w2,
                     const float* __restrict__ b2,
                     const float* __restrict__ W_ih,
                     const float* __restrict__ W_hh,
                     const float* __restrict__ b_ih,
                     const float* __restrict__ b_hh,
                     const float* __restrict__ wg,
                     const float* __restrict__ bg,
                     float* __restrict__ out)
{
    // h double buffer: 2 x 16 rows(cells) x 144B (64 bf16 + pad)
    __shared__ __align__(16) char hbuf[2 * 16 * 144];

    const int tid  = threadIdx.x;
    const int wv   = tid >> 6;          // 0..3: 16-hdim slice
    const int lane = tid & 63;
    const int lo   = lane & 15;
    const int hi   = lane >> 4;

    for (int o = tid; o < (2 * 16 * 144) / 4; o += 256)
        ((unsigned*)hbuf)[o] = 0u;      // h0 = 0 (both buffers)

    // ---- per-cell constants ----
    const int cell = blockIdx.x * 16 + lo;
    const int n    = cell & 63;
    float a_n = 0.f, c_n = 0.f;
    #pragma unroll
    for (int k = 0; k < 10; ++k) {
        a_n += w1[n * 10 + k] * w2[n * 10 + k];   // per-neuron affine collapse
        c_n += b1[n * 10 + k] * w2[n * 10 + k];
    }
    c_n += b2[n];
    const float bgv = bg[0];

    // ---- A-fragments resident in VGPRs ----
    bf16x8 AWf[4][3];
    #pragma unroll
    for (int g = 0; g < 4; ++g) {
        const int row = (g * 4 + wv) * 16 + lo;
        #pragma unroll
        for (int kk = 0; kk < 2; ++kk) {
            const float* src = W_hh + row * 64 + kk * 32 + hi * 8;
            bf16x8 v;
            #pragma unroll
            for (int e = 0; e < 8; ++e) v[e] = f2bf(src[e]);
            AWf[g][kk] = v;
        }
        bf16x8 vx = {};                 // K-ext: col64 = W_ih, col65 = bias
        if (hi == 0) {
            vx[0] = f2bf(W_ih[row]);
            vx[1] = f2bf(b_ih[row] + b_hh[row]);
        }
        AWf[g][2] = vx;
    }
    // g-dot A-frags: row 0 = wg (lanes lo==0), rows 1..15 = 0
    bf16x8 AWg[2];
    #pragma unroll
    for (int kk = 0; kk < 2; ++kk) {
        bf16x8 v = {};
        if (lo == 0) {
            const float* src = wg + kk * 32 + hi * 8;
            #pragma unroll
            for (int e = 0; e < 8; ++e) v[e] = f2bf(src[e]);
        }
        AWg[kk] = v;
    }

    const f32x4 zero4 = {0.f, 0.f, 0.f, 0.f};
    f32x4 cst = zero4;
    float sp0 = 0.f;                    // softplus at t=0 (held by wave 1)
    float gA  = 0.f;                    // accg[0] from previous step = g_{t-2}
    const float* inP  = input + cell;
    float*       outP = out + cell;
    float raw_next = inP[0];

    __syncthreads();

    for (int t = 0; t < TT; ++t) {
        const float raw = raw_next;
        raw_next = inP[((t + 1) & (TT - 1)) * MCELLS];
        const float x = raw * a_n + c_n;            // outLin[t,cell]

        // B-ext frag: rows 64..95 of B = [x, 1, 0...] (per cell = lo)
        u32x4 bxi = {0u, 0u, 0u, 0u};
        bxi[0] = (hi == 0) ? cvtpk(x, 1.0f) : 0u;
        const bf16x8 bx = __builtin_bit_cast(bf16x8, bxi);

        // h B-frags: cell = lo, hdims hi*8.. / 32+hi*8..
        const char* hrd = hbuf + (t & 1) * 2304 + lo * 144;
        const bf16x8 bf0 = *(const bf16x8*)(hrd + hi * 16);
        const bf16x8 bf1 = *(const bf16x8*)(hrd + 64 + hi * 16);

        f32x4 acc[4];
        #pragma unroll
        for (int g = 0; g < 4; ++g) {
            acc[g] = __builtin_amdgcn_mfma_f32_16x16x32_bf16(AWf[g][2], bx,  zero4, 0, 0, 0);
            acc[g] = __builtin_amdgcn_mfma_f32_16x16x32_bf16(AWf[g][0], bf0, acc[g], 0, 0, 0);
            acc[g] = __builtin_amdgcn_mfma_f32_16x16x32_bf16(AWf[g][1], bf1, acc[g], 0, 0, 0);
        }
        // g_{t-1} = wg . h_t  (row 0 -> lanes hi==0, reg 0)
        f32x4 accg;
        accg = __builtin_amdgcn_mfma_f32_16x16x32_bf16(AWg[0], bf0, zero4, 0, 0, 0);
        accg = __builtin_amdgcn_mfma_f32_16x16x32_bf16(AWg[1], bf1, accg, 0, 0, 0);

        // activations: lane handles (cell=lo, hdim = wv*16 + hi*4 + r)
        float hv[4];
        #pragma unroll
        for (int r = 0; r < 4; ++r) {
            const float ip = acc[0][r];
            const float fp = acc[1][r];
            const float gp = acc[2][r];
            const float op = acc[3][r];

            const float Ei  = __builtin_amdgcn_exp2f(-LOG2E * ip);
            const float Ef  = __builtin_amdgcn_exp2f(-LOG2E * fp);
            const float gpc = __builtin_amdgcn_fmed3f(gp, -15.f, 15.f);
            const float Eg  = __builtin_amdgcn_exp2f(2.f * LOG2E * gpc);
            // c' = sig(f)*c + sig(i)*tanh(g), single rcp:
            const float D1  = 1.f + Ef;
            const float D2  = (Eg + 1.f) * (1.f + Ei);
            const float num = cst[r] * D2 + (Eg - 1.f) * D1;
            const float cp  = num * __builtin_amdgcn_rcpf(D1 * D2);
            cst[r] = cp;
            const float cpc = __builtin_amdgcn_fmed3f(cp, -15.f, 15.f);
            const float Ec  = __builtin_amdgcn_exp2f(2.f * LOG2E * cpc);
            const float Eo  = __builtin_amdgcn_exp2f(-LOG2E * op);
            // h = sig(o)*tanh(c), single rcp:
            hv[r] = (Ec - 1.f) *
                __builtin_amdgcn_rcpf((Ec + 1.f) * (1.f + Eo));
        }
        // h-write: hdims wv*16 + hi*4 .. +4 at row lo
        uint2 pk;
        pk.x = cvtpk(hv[0], hv[1]);
        pk.y = cvtpk(hv[2], hv[3]);
        *(uint2*)(hbuf + ((t + 1) & 1) * 2304 + lo * 144 + wv * 32 + hi * 8) = pk;

        // output: out[t] = g_prev[t]*softplus(x-1); g_prev = {g_0, 1, g_{t-2}..}
        // round-robin: wave (t&3) handles step t (t=0 handled by wave 1).
        if (((t == 0) ? (wv == 1) : ((t & 3) == wv)) && hi == 0) {
            const float spE = __builtin_amdgcn_exp2f(LOG2E * (x - 1.f));
            const float sp  = LN2 * __builtin_amdgcn_logf(1.f + spE);
            if (t == 0) {
                sp0 = sp;                               // wave 1 holds sp_0
            } else if (t == 1) {
                outP[MCELLS] = sp;                      // g_prev[1] = 1
                outP[0] = (accg[0] + bgv) * sp0;        // g_0 * sp_0 (fresh accg)
            } else {
                outP[t * MCELLS] = (gA + bgv) * sp;     // g_{t-2} * sp_t
            }
        }
        gA = accg[0];                   // delay register: g_{t-1} for next step
        __syncthreads();                // h(t+1) visible to all waves
    }
}

extern "C" void kernel_launch(void* const* d_in, const int* in_sizes, int n_in,
                              void* d_out, int out_size, void* d_ws, size_t ws_size,
                              hipStream_t stream) {
    const float* input = (const float*)d_in[0];
    const float* w1    = (const float*)d_in[1];
    const float* b1    = (const float*)d_in[2];
    const float* w2    = (const float*)d_in[3];
    const float* b2    = (const float*)d_in[4];
    const float* W_ih  = (const float*)d_in[5];
    const float* W_hh  = (const float*)d_in[6];
    const float* b_ih  = (const float*)d_in[7];
    const float* b_hh  = (const float*)d_in[8];
    const float* wg    = (const float*)d_in[9];
    const float* bg    = (const float*)d_in[10];

    lstm_net_kernel<<<dim3(1024), dim3(256), 0, stream>>>(
        input, w1, b1, w2, b2, W_ih, W_hh, b_ih, b_hh, wg, bg, (float*)d_out);
}

// Round 10
// 710.042 us; speedup vs baseline: 1.2078x; 1.0346x over previous
//
#include <hip/hip_runtime.h>
#include <hip/hip_bf16.h>

#define TT 512
#define MCELLS 16384            // B*N = 256*64
#define LOG2E 1.44269504088896340736f
#define LN2   0.69314718055994530942f

typedef __attribute__((ext_vector_type(8))) short bf16x8;
typedef __attribute__((ext_vector_type(4))) float f32x4;
typedef __attribute__((ext_vector_type(4))) unsigned u32x4;

__device__ __forceinline__ short f2bf(float f) {
    __hip_bfloat16 h = __float2bfloat16(f);
    return __builtin_bit_cast(short, h);
}
// two f32 -> packed bf16 dword (low16 = a, high16 = b), RNE in HW
__device__ __forceinline__ unsigned cvtpk(float a, float b) {
    unsigned r;
    asm("v_cvt_pk_bf16_f32 %0, %1, %2" : "=v"(r) : "v"(a), "v"(b));
    return r;
}

// Persistent LSTM. grid = 1024 blocks x 256 threads (4 waves). Block owns 16
// cells (cell = blockIdx*16 + (lane&15)); wave w handles hdims [w*16, w*16+16)
// for all 4 gates (jm tile = gate*4 + w). Swapped MFMA D[gate-rows, cell],
// A = W_hh VGPR-resident, B = h^T from LDS. K=96: 3rd MFMA carries
// x*W_ih + bias. g_t = h.wg via 2 extra MFMAs.
// BISECT ROUND: sigmoids via exp2 (exact R7 algebra); ONLY tanh via LDS LUT
// (direct array indexing, domain [-8,8], step 1/128). R8/R9's full-LUT failed
// at 3.2e-2 with sigma-table-invariant signature; this arm validates the LUT
// mechanism + tanh table in isolation while keeping a passing baseline.
__global__ __launch_bounds__(256, 4)
void lstm_net_kernel(const float* __restrict__ input,
                     const float* __restrict__ w1,
                     const float* __restrict__ b1,
                     const float* __restrict__ w2,
                     const float* __restrict__ b2,
                     const float* __restrict__ W_ih,
                     const float* __restrict__ W_hh,
                     const float* __restrict__ b_ih,
                     const float* __restrict__ b_hh,
                     const float* __restrict__ wg,
                     const float* __restrict__ bg,
                     float* __restrict__ out)
{
    __shared__ float tanY[2049];
    __shared__ float tanD[2049];
    // h double buffer: 2 x 16 rows(cells) x 144B (64 bf16 + pad)
    __shared__ __align__(16) char hbuf[2 * 16 * 144];

    const int tid  = threadIdx.x;
    const int wv   = tid >> 6;          // 0..3: 16-hdim slice
    const int lane = tid & 63;
    const int lo   = lane & 15;
    const int hi   = lane >> 4;

    // ---- build tanh table (one-time): tanh on [-8, 8], step 1/128 ----
    for (int idx = tid; idx < 2049; idx += 256) {
        const float xv = (float)idx * 0.0078125f - 8.0f;
        const float e0 = __builtin_amdgcn_exp2f(2.0f * LOG2E * xv);
        const float e1 = __builtin_amdgcn_exp2f(2.0f * LOG2E * (xv + 0.0078125f));
        const float t0 = 1.0f - 2.0f / (1.0f + e0);
        const float t1 = 1.0f - 2.0f / (1.0f + e1);
        tanY[idx] = t0;
        tanD[idx] = t1 - t0;
    }

    for (int o = tid; o < (2 * 16 * 144) / 4; o += 256)
        ((unsigned*)hbuf)[o] = 0u;      // h0 = 0 (both buffers)

    // ---- per-cell constants ----
    const int cell = blockIdx.x * 16 + lo;
    const int n    = cell & 63;
    float a_n = 0.f, c_n = 0.f;
    #pragma unroll
    for (int k = 0; k < 10; ++k) {
        a_n += w1[n * 10 + k] * w2[n * 10 + k];   // per-neuron affine collapse
        c_n += b1[n * 10 + k] * w2[n * 10 + k];
    }
    c_n += b2[n];
    const float bgv = bg[0];

    // ---- A-fragments resident in VGPRs ----
    bf16x8 AWf[4][3];
    #pragma unroll
    for (int g = 0; g < 4; ++g) {
        const int row = (g * 4 + wv) * 16 + lo;
        #pragma unroll
        for (int kk = 0; kk < 2; ++kk) {
            const float* src = W_hh + row * 64 + kk * 32 + hi * 8;
            bf16x8 v;
            #pragma unroll
            for (int e = 0; e < 8; ++e) v[e] = f2bf(src[e]);
            AWf[g][kk] = v;
        }
        bf16x8 vx = {};                 // K-ext: col64 = W_ih, col65 = bias
        if (hi == 0) {
            vx[0] = f2bf(W_ih[row]);
            vx[1] = f2bf(b_ih[row] + b_hh[row]);
        }
        AWf[g][2] = vx;
    }
    // g-dot A-frags: row 0 = wg (lanes lo==0), rows 1..15 = 0
    bf16x8 AWg[2];
    #pragma unroll
    for (int kk = 0; kk < 2; ++kk) {
        bf16x8 v = {};
        if (lo == 0) {
            const float* src = wg + kk * 32 + hi * 8;
            #pragma unroll
            for (int e = 0; e < 8; ++e) v[e] = f2bf(src[e]);
        }
        AWg[kk] = v;
    }

    const f32x4 zero4 = {0.f, 0.f, 0.f, 0.f};
    f32x4 cst = zero4;
    float sp0 = 0.f;                    // softplus at t=0 (held by wave 1)
    float gA  = 0.f;                    // g from previous step
    const float* inP  = input + cell;
    float*       outP = out + cell;
    float raw_next = inP[0];

    __syncthreads();                    // table + h0 visible

    for (int t = 0; t < TT; ++t) {
        const float raw = raw_next;
        raw_next = inP[((t + 1) & (TT - 1)) * MCELLS];
        const float x = raw * a_n + c_n;            // outLin[t,cell]

        // B-ext frag: rows 64..95 of B = [x, 1, 0...] (per cell = lo)
        u32x4 bxi = {0u, 0u, 0u, 0u};
        bxi[0] = (hi == 0) ? cvtpk(x, 1.0f) : 0u;
        const bf16x8 bx = __builtin_bit_cast(bf16x8, bxi);

        // h B-frags: cell = lo, hdims hi*8.. / 32+hi*8..
        const char* hrd = hbuf + (t & 1) * 2304 + lo * 144;
        const bf16x8 bf0 = *(const bf16x8*)(hrd + hi * 16);
        const bf16x8 bf1 = *(const bf16x8*)(hrd + 64 + hi * 16);

        f32x4 acc[4];
        #pragma unroll
        for (int g = 0; g < 4; ++g) {
            acc[g] = __builtin_amdgcn_mfma_f32_16x16x32_bf16(AWf[g][2], bx,  zero4, 0, 0, 0);
            acc[g] = __builtin_amdgcn_mfma_f32_16x16x32_bf16(AWf[g][0], bf0, acc[g], 0, 0, 0);
            acc[g] = __builtin_amdgcn_mfma_f32_16x16x32_bf16(AWf[g][1], bf1, acc[g], 0, 0, 0);
        }
        // g_t = wg . h  (row 0 -> lanes hi==0, reg 0)
        f32x4 accg;
        accg = __builtin_amdgcn_mfma_f32_16x16x32_bf16(AWg[0], bf0, zero4, 0, 0, 0);
        accg = __builtin_amdgcn_mfma_f32_16x16x32_bf16(AWg[1], bf1, accg, 0, 0, 0);

        // activations: lane handles (cell=lo, hdim = wv*16 + hi*4 + r)
        // sigma via exp2 (trans), tanh via direct-indexed LDS LUT.
        float hv[4];
        #pragma unroll
        for (int r = 0; r < 4; ++r) {
            const float ip = acc[0][r];
            const float fp = acc[1][r];
            const float gp = acc[2][r];
            const float op = acc[3][r];

            const float Ei = __builtin_amdgcn_exp2f(-LOG2E * ip);
            const float Ef = __builtin_amdgcn_exp2f(-LOG2E * fp);
            const float Eo = __builtin_amdgcn_exp2f(-LOG2E * op);

            // tanh(g) via LUT
            const float gcl = __builtin_amdgcn_fmed3f(gp, -8.0f, 7.9921875f);
            const float gu  = fmaf(gcl, 128.0f, 1024.0f);
            const int   gi  = (int)gu;
            const float gfr = gu - (float)gi;
            const float tg  = fmaf(gfr, tanD[gi], tanY[gi]);

            // cp = c*sig(f) + tg*sig(i) = [c*(1+Ei) + tg*(1+Ef)]*rcp((1+Ei)(1+Ef))
            const float A1 = 1.f + Ei;
            const float A2 = 1.f + Ef;
            const float cp = (cst[r] * A1 + tg * A2) *
                             __builtin_amdgcn_rcpf(A1 * A2);
            cst[r] = cp;

            // tanh(cp) via LUT
            const float ccl = __builtin_amdgcn_fmed3f(cp, -8.0f, 7.9921875f);
            const float cu  = fmaf(ccl, 128.0f, 1024.0f);
            const int   ci  = (int)cu;
            const float cfr = cu - (float)ci;
            const float tc  = fmaf(cfr, tanD[ci], tanY[ci]);

            hv[r] = tc * __builtin_amdgcn_rcpf(1.f + Eo);
        }
        // h-write: hdims wv*16 + hi*4 .. +4 at row lo
        uint2 pk;
        pk.x = cvtpk(hv[0], hv[1]);
        pk.y = cvtpk(hv[2], hv[3]);
        *(uint2*)(hbuf + ((t + 1) & 1) * 2304 + lo * 144 + wv * 32 + hi * 8) = pk;

        // output: out[t] = g_prev[t]*softplus(x-1); g_prev = {g_0, 1, g_{t-2}..}
        // round-robin: wave (t&3) handles step t (t=0 handled by wave 1).
        if (((t == 0) ? (wv == 1) : ((t & 3) == wv)) && hi == 0) {
            const float spE = __builtin_amdgcn_exp2f(LOG2E * (x - 1.f));
            const float sp  = LN2 * __builtin_amdgcn_logf(1.f + spE);
            if (t == 0) {
                sp0 = sp;                               // wave 1 holds sp_0
            } else if (t == 1) {
                outP[MCELLS] = sp;                      // g_prev[1] = 1
                outP[0] = (accg[0] + bgv) * sp0;        // g_0 * sp_0 (fresh accg)
            } else {
                outP[t * MCELLS] = (gA + bgv) * sp;     // g_{t-2} * sp_t
            }
        }
        gA = accg[0];                   // delay register: g_{t-1} for next step
        __syncthreads();                // h(t+1) visible to all waves
    }
}

extern "C" void kernel_launch(void* const* d_in, const int* in_sizes, int n_in,
                              void* d_out, int out_size, void* d_ws, size_t ws_size,
                              hipStream_t stream) {
    const float* input = (const float*)d_in[0];
    const float* w1    = (const float*)d_in[1];
    const float* b1    = (const float*)d_in[2];
    const float* w2    = (const float*)d_in[3];
    const float* b2    = (const float*)d_in[4];
    const float* W_ih  = (const float*)d_in[5];
    const float* W_hh  = (const float*)d_in[6];
    const float* b_ih  = (const float*)d_in[7];
    const float* b_hh  = (const float*)d_in[8];
    const float* wg    = (const float*)d_in[9];
    const float* bg    = (const float*)d_in[10];

    lstm_net_kernel<<<dim3(1024), dim3(256), 0, stream>>>(
        input, w1, b1, w2, b2, W_ih, W_hh, b_ih, b_hh, wg, bg, (float*)d_out);
}